// Round 10
// baseline (304.056 us; speedup 1.0000x reference)
//
#include <hip/hip_runtime.h>
#include <hip/hip_fp16.h>

#define N_NODES 100000
#define N_EDGES 1600000
#define E_TOT   (N_EDGES + N_NODES)   // 1,700,000 incl. self-loops
#define NEG_SLOPE 0.2f
#define PART_EPB 4096                 // edges per partition block
#define NBUCK 391                     // 256-node buckets (R7)
#define PBSTRIDE 5376                 // slots/bucket: mean 4352 + ~15 sigma
#define NGEMM ((N_NODES + 63) / 64)   // 1563 gemm blocks (64 rows each, R7)
#define NPART ((E_TOT + PART_EPB - 1) / PART_EPB)   // 416 partition blocks

using f16x8 = __attribute__((ext_vector_type(8))) _Float16;
using f32x4 = __attribute__((ext_vector_type(4))) float;
union H8 { f16x8 v; _Float16 h[8]; __half2 h2[4]; };
union H4 { __half2 h2[2]; uint2 u; };

// Journal: R5 bundle +52us (serial prep + wave-0 MFMA imbalance — but fp16
// WaT numerics VERIFIED, absmax unchanged); R6 +14; R7 391-bucket fill -1.8
// (kept); R8 M=128 +9 (occupancy); R9 W1T tables ~neutral (W-loads not the
// bottleneck). R10 = R9 + BALANCED WaT1 tile: wave w computes the al/ar
// MFMA tile for its own m-group (+4 MFMA/wave) and the 128-shuffle/wave
// epilogue is deleted. Prep stays fully parallel (10 blocks).

// ---------------------------------------------------------------------------
// k_prep: parallel (10 blocks x 256) — replaces the ibcnt memset.
//   blocks 0..7: W1T[j][k] = (f16)W1[k][j]   (128x128, 32KB)
//   block  8   : W2T[j][k] = (f16)W2[k][j]   (16x128, 4KB) + zero bcnt
//   block  9   : WaT1[n][k] (16x128 f16): n<4 -> sum_c W1[k][n*32+c]*as1[n*32+c]
//                n=4..7 -> same with ad1; n=8..15 -> 0.  (al = x @ (W1·a))
// ---------------------------------------------------------------------------
__global__ __launch_bounds__(256)
void k_prep(const float* __restrict__ W1, const float* __restrict__ W2,
            const float* __restrict__ as1, const float* __restrict__ ad1,
            _Float16* __restrict__ W1T, _Float16* __restrict__ W2T,
            _Float16* __restrict__ WaT1, int* __restrict__ bcnt) {
    const int t = threadIdx.x;
    if (blockIdx.x < 8) {
        const int g = (int)blockIdx.x * 256 + t;   // 0..2047
        const int j = g & 127;                     // coalesced reads over j
        const int kb = g >> 7;                     // 0..15
        H8 o;
#pragma unroll
        for (int i = 0; i < 8; ++i)
            o.h[i] = (_Float16)W1[(size_t)(kb * 8 + i) * 128 + j];
        *(f16x8*)&W1T[(size_t)j * 128 + kb * 8] = o.v;   // 16B store
        return;
    }
    if (blockIdx.x == 8) {
        // W2T + bcnt zero
        for (int i = t; i < 512; i += 256) bcnt[i] = 0;
        const int j = t & 15, kb = t >> 4;             // 256 threads = 16x16
        H8 o;
#pragma unroll
        for (int i = 0; i < 8; ++i)
            o.h[i] = (_Float16)W2[(size_t)(kb * 8 + i) * 16 + j];
        *(f16x8*)&W2T[(size_t)j * 128 + kb * 8] = o.v;
        return;
    }
    // block 9: WaT1 (8 rows x 128 cols of 32-dots; rows 8-15 zero)
    for (int item = t; item < 1024; item += 256) {
        const int h = item >> 7;                   // 0..7
        const int k = item & 127;
        const float* av = (h < 4) ? &as1[(h & 3) * 32] : &ad1[(h & 3) * 32];
        const float* wr = &W1[(size_t)k * 128 + (h & 3) * 32];
        float s = 0.f;
#pragma unroll
        for (int c = 0; c < 32; ++c) s += wr[c] * av[c];
        WaT1[h * 128 + k] = (_Float16)s;
    }
    if (t < 128) {
#pragma unroll
        for (int r = 8; r < 16; ++r) WaT1[r * 128 + t] = (_Float16)0.f;
    }
}

// ---------------------------------------------------------------------------
// Merged kernel: blocks < NGEMM do the layer-1 GEMM via MFMA (staged-x LDS
// tile, M=64 — R7). Blocks >= NGEMM do the edge bucket-partition.
// R10: al1/ar1 via balanced WaT1 MFMA tile — wave w owns m-group w's
// e-tile (+1 MFMA +1 ds_read per kt). The 128-shuffle/wave epilogue is gone.
// ---------------------------------------------------------------------------
__global__ __launch_bounds__(256)
void k_gemm1_part(const float* __restrict__ x, const _Float16* __restrict__ W1T,
                  const _Float16* __restrict__ WaT1,
                  const int* __restrict__ ei, int* __restrict__ bcnt, int* __restrict__ pairs,
                  __half* __restrict__ xw1h, float* __restrict__ al1, float* __restrict__ ar1) {
    __shared__ int lcnt[NBUCK + 1];
    __shared__ int lbase[NBUCK + 1];
    __shared__ _Float16 sx[64][136];         // 17.4 KB; 272B row stride (2-way = free, m136)
    const int t = threadIdx.x;

    if (blockIdx.x >= NGEMM) {
        // ===== edge-partition role (R7 code; 391 buckets of 256 nodes) =====
        const int base = ((int)blockIdx.x - NGEMM) * PART_EPB;
        for (int i = t; i < NBUCK; i += 256) lcnt[i] = 0;
        __syncthreads();
        int sr[16], dr[16];
#pragma unroll
        for (int u = 0; u < 16; ++u) {
            const int e = base + u * 256 + t;    // coalesced
            if (e < E_TOT) {
                int s, d;
                if (e < N_EDGES) { s = ei[e]; d = ei[N_EDGES + e]; }
                else             { s = d = e - N_EDGES; }
                sr[u] = s; dr[u] = d;
                atomicAdd(&lcnt[d >> 8], 1);     // LDS
            } else dr[u] = -1;
        }
        __syncthreads();
        for (int i = t; i < NBUCK; i += 256) {
            const int c = lcnt[i];
            lbase[i] = (c > 0) ? atomicAdd(&bcnt[i], c) : 0;   // global, 1/bucket
            lcnt[i] = 0;
        }
        __syncthreads();
#pragma unroll
        for (int u = 0; u < 16; ++u) {
            if (dr[u] >= 0) {
                const int bk = dr[u] >> 8;
                const int r = atomicAdd(&lcnt[bk], 1);         // LDS
                pairs[(size_t)bk * PBSTRIDE + lbase[bk] + r] = (sr[u] << 8) | (dr[u] & 255);
            }
        }
        return;
    }

    // ===== MFMA GEMM role (R7 structure, W1T B-loads, WaT1 e-tile) =====
    const int n0 = (int)blockIdx.x * 64;

    // Cooperative stage: 64 rows x 128 cols, f32 -> f16, coalesced float4.
    for (int i = t; i < 64 * 32; i += 256) {           // 8 iters/thread
        const int row = i >> 5;
        const int c4 = (i & 31) * 4;
        const int gr = n0 + row;
        const float4 xv = *(const float4*)&x[(size_t)(gr < N_NODES ? gr : N_NODES - 1) * 128 + c4];
        H4 tmp;
        tmp.h2[0] = __float22half2_rn(make_float2(xv.x, xv.y));
        tmp.h2[1] = __float22half2_rn(make_float2(xv.z, xv.w));
        *(uint2*)&sx[row][c4] = tmp.u;                 // 8B, 8B-aligned
    }
    __syncthreads();

    const int lane = t & 63;
    const int w = t >> 6;                    // wave id == head id
    const int q = lane >> 4;                 // quad
    const int n15 = lane & 15;
    const int j0 = (2 * w) * 16 + n15;       // col in tile 0 of this head
    const int j1 = (2 * w + 1) * 16 + n15;   // col in tile 1

    f32x4 acc[4][2] = {};                    // [m-group][n-tile]; static indices only
    f32x4 e = {0.f, 0.f, 0.f, 0.f};          // al/ar tile for m-group w

    for (int kt = 0; kt < 4; ++kt) {
        const int k0 = kt * 32 + q * 8;
        H8 A0, A1, A2, A3, AW, B0, B1, BW;
        A0.v = *(const f16x8*)&sx[n15][k0];            // 16B ds_read_b128
        A1.v = *(const f16x8*)&sx[16 + n15][k0];
        A2.v = *(const f16x8*)&sx[32 + n15][k0];
        A3.v = *(const f16x8*)&sx[48 + n15][k0];
        AW.v = *(const f16x8*)&sx[w * 16 + n15][k0];   // this wave's m-group (wave-uniform row base)
        B0.v = *(const f16x8*)&W1T[(size_t)j0 * 128 + k0];   // 16B, L1-hot (32KB table)
        B1.v = *(const f16x8*)&W1T[(size_t)j1 * 128 + k0];
        BW.v = *(const f16x8*)&WaT1[(size_t)n15 * 128 + k0]; // 4KB, L1-hot
        acc[0][0] = __builtin_amdgcn_mfma_f32_16x16x32_f16(A0.v, B0.v, acc[0][0], 0, 0, 0);
        acc[0][1] = __builtin_amdgcn_mfma_f32_16x16x32_f16(A0.v, B1.v, acc[0][1], 0, 0, 0);
        acc[1][0] = __builtin_amdgcn_mfma_f32_16x16x32_f16(A1.v, B0.v, acc[1][0], 0, 0, 0);
        acc[1][1] = __builtin_amdgcn_mfma_f32_16x16x32_f16(A1.v, B1.v, acc[1][1], 0, 0, 0);
        acc[2][0] = __builtin_amdgcn_mfma_f32_16x16x32_f16(A2.v, B0.v, acc[2][0], 0, 0, 0);
        acc[2][1] = __builtin_amdgcn_mfma_f32_16x16x32_f16(A2.v, B1.v, acc[2][1], 0, 0, 0);
        acc[3][0] = __builtin_amdgcn_mfma_f32_16x16x32_f16(A3.v, B0.v, acc[3][0], 0, 0, 0);
        acc[3][1] = __builtin_amdgcn_mfma_f32_16x16x32_f16(A3.v, B1.v, acc[3][1], 0, 0, 0);
        e = __builtin_amdgcn_mfma_f32_16x16x32_f16(AW.v, BW.v, e, 0, 0, 0);
    }

    // Epilogue: D col = n15-based j, row m*16 + q*4 + r. STORES ONLY.
#pragma unroll
    for (int m = 0; m < 4; ++m) {
#pragma unroll
        for (int r = 0; r < 4; ++r) {
            const int node = n0 + m * 16 + q * 4 + r;
            if (node < N_NODES) {
                xw1h[(size_t)node * 128 + j0] = __float2half(acc[m][0][r]);   // 32B runs/quad
                xw1h[(size_t)node * 128 + j1] = __float2half(acc[m][1][r]);
            }
        }
    }
    // e-tile: col n15 0-3 = al head n15, 4-7 = ar head n15-4; row = q*4+r of
    // m-group w. 16B runs per quad.
#pragma unroll
    for (int r = 0; r < 4; ++r) {
        const int node = n0 + w * 16 + q * 4 + r;
        if (node < N_NODES) {
            if (n15 < 4)      al1[(size_t)node * 4 + n15] = e[r];
            else if (n15 < 8) ar1[(size_t)node * 4 + (n15 - 4)] = e[r];
        }
    }
}

// ---------------------------------------------------------------------------
// k_fill3 (R7): one 256-thread block per 256-node bucket -> 391 blocks.
// LDS histogram + cursors counting sort; emits ioff/deg/ssrc.
// ---------------------------------------------------------------------------
__global__ __launch_bounds__(256)
void k_fill3(const int* __restrict__ pairs, const int* __restrict__ bcnt,
             int* __restrict__ ioff, int* __restrict__ deg, int* __restrict__ ssrc) {
    const int bucket = blockIdx.x;
    const int t = threadIdx.x;
    const int cnt = bcnt[bucket];
    __shared__ int lhist[256];
    __shared__ int lcur[256];
    __shared__ int wsum[4];
    __shared__ int sbc[NBUCK + 1];
    __shared__ int sbase;
    lhist[t] = 0;
    for (int i = t; i < NBUCK; i += 256) sbc[i] = bcnt[i];   // coalesced stage
    __syncthreads();
    if (t == 0) {                            // edges in all lower buckets (LDS, pipelined)
        int b = 0;
        for (int k = 0; k < bucket; ++k) b += sbc[k];
        sbase = b;
    }
    for (int i = t; i < cnt; i += 256) {
        const int p = pairs[(size_t)bucket * PBSTRIDE + i];
        atomicAdd(&lhist[p & 255], 1);
    }
    __syncthreads();
    const int v = lhist[t];
    int inc = v;
    const int lane = t & 63, wid = t >> 6;
#pragma unroll
    for (int o = 1; o < 64; o <<= 1) {
        const int nv = __shfl_up(inc, o, 64);
        if (lane >= o) inc += nv;
    }
    if (lane == 63) wsum[wid] = inc;
    __syncthreads();
    if (t == 0) {
        int acc = 0;
#pragma unroll
        for (int k = 0; k < 4; ++k) { const int tv = wsum[k]; wsum[k] = acc; acc += tv; }
    }
    __syncthreads();
    const int gofs = sbase + (inc - v) + wsum[wid];   // global CSR offset of node d
    const int d = bucket * 256 + t;
    if (d < N_NODES) { ioff[d] = gofs; deg[d] = v; }
    lcur[t] = gofs;
    __syncthreads();
    for (int i = t; i < cnt; i += 256) {
        const int p = pairs[(size_t)bucket * PBSTRIDE + i];
        const int pos = atomicAdd(&lcur[p & 255], 1);      // LDS
        ssrc[pos] = p >> 8;
    }
}

// ---------------------------------------------------------------------------
// Layer 1 pull-aggregation — FROZEN (R10: VGPR 20, no epilogue preload;
// R1: no layer-2 fusion; R3: MLP-widening is a no-op -> per-CU miss-queue
// bound). One wave per dst node, zero barriers; uint4 gathers, 8 in flight.
// ---------------------------------------------------------------------------
__global__ __launch_bounds__(256)
void k_aggr1(const int* __restrict__ ssrc, const int* __restrict__ offs,
             const int* __restrict__ deg, const float* __restrict__ al1,
             const float* __restrict__ ar1, const __half* __restrict__ xw1h,
             const float* __restrict__ b1, __half* __restrict__ out1h) {
    const int lane = threadIdx.x & 63;
    const int d = blockIdx.x * 4 + (threadIdx.x >> 6);
    const int g = lane >> 4;                 // edge group 0..3
    const int c = lane & 15;                 // col group: features 8c..8c+7
    const int h = c >> 2;                    // head of this col group
    const int beg = offs[d];
    const int n = deg[d];
    const float arh = ar1[(size_t)d * 4 + h];
    float acc[8] = {0.f, 0.f, 0.f, 0.f, 0.f, 0.f, 0.f, 0.f};
    float dnm = 0.f;

    for (int base = 0; base < n; base += 8) {
#pragma unroll
        for (int u = 0; u < 2; ++u) {
            const int e = base + u * 4 + g;
            const bool p = e < n;
            const int s = ssrc[beg + (p ? e : 0)];         // L1-hot (sequential)
            float v = al1[(size_t)s * 4 + h] + arh;        // broadcast gather
            v = v > 0.f ? v : NEG_SLOPE * v;
            const float w = p ? __expf(v) : 0.f;
            const uint4 rv = *(const uint4*)&xw1h[(size_t)s * 128 + c * 8];
            const float2 f0 = __half22float2(*(const __half2*)&rv.x);
            const float2 f1 = __half22float2(*(const __half2*)&rv.y);
            const float2 f2 = __half22float2(*(const __half2*)&rv.z);
            const float2 f3 = __half22float2(*(const __half2*)&rv.w);
            acc[0] = fmaf(w, f0.x, acc[0]); acc[1] = fmaf(w, f0.y, acc[1]);
            acc[2] = fmaf(w, f1.x, acc[2]); acc[3] = fmaf(w, f1.y, acc[3]);
            acc[4] = fmaf(w, f2.x, acc[4]); acc[5] = fmaf(w, f2.y, acc[5]);
            acc[6] = fmaf(w, f3.x, acc[6]); acc[7] = fmaf(w, f3.y, acc[7]);
            dnm += w;
        }
    }
#pragma unroll
    for (int i = 0; i < 8; ++i) {
        acc[i] += __shfl_xor(acc[i], 16, 64);
        acc[i] += __shfl_xor(acc[i], 32, 64);
    }
    dnm += __shfl_xor(dnm, 16, 64);
    dnm += __shfl_xor(dnm, 32, 64);
    if (g == 0) {
        const float rc = 1.f / dnm;
        const float4 b01 = *(const float4*)&b1[c * 8];
        const float4 b23 = *(const float4*)&b1[c * 8 + 4];
        const float bb[8] = {b01.x, b01.y, b01.z, b01.w, b23.x, b23.y, b23.z, b23.w};
        __half ho[8];
#pragma unroll
        for (int i = 0; i < 8; ++i) {
            const float hv = acc[i] * rc + bb[i];
            ho[i] = __float2half(hv > 0.f ? hv : 0.f);     // bias + ReLU
        }
        *(uint4*)&out1h[(size_t)d * 128 + c * 8] = *(uint4*)ho;
    }
}

// ---------------------------------------------------------------------------
// Layer 2 GEMM via MFMA. 128 nodes/block, 4 waves, 2 M-tiles/wave (R7).
// B-fragment is a direct 16B load of W2T (4KB, L1-hot) (R9).
// ---------------------------------------------------------------------------
__global__ __launch_bounds__(256)
void k_gemm2m(const __half* __restrict__ out1h, const _Float16* __restrict__ W2T,
              const float* __restrict__ a_src2, const float* __restrict__ a_dst2,
              __half* __restrict__ xw2h, float* __restrict__ al2, float* __restrict__ ar2) {
    const int t = threadIdx.x;
    const int lane = t & 63;
    const int w = t >> 6;
    const int q = lane >> 4;
    const int n15 = lane & 15;
    const int n0 = (int)blockIdx.x * 128 + w * 16;
    const int ra0 = n0 + n15;
    const int ra1 = n0 + 64 + n15;
    const size_t rowA0 = (ra0 < N_NODES) ? (size_t)ra0 : (size_t)(N_NODES - 1);
    const size_t rowA1 = (ra1 < N_NODES) ? (size_t)ra1 : (size_t)(N_NODES - 1);

    f32x4 acc0 = {0.f, 0.f, 0.f, 0.f}, acc1 = acc0;
#pragma unroll
    for (int kt = 0; kt < 4; ++kt) {
        const int k0 = kt * 32 + q * 8;
        H8 A0, A1, B;
        A0.v = *(const f16x8*)&out1h[rowA0 * 128 + k0];    // 16B, 32B runs/quad
        A1.v = *(const f16x8*)&out1h[rowA1 * 128 + k0];
        B.v  = *(const f16x8*)&W2T[(size_t)n15 * 128 + k0];  // 16B, L1-hot
        acc0 = __builtin_amdgcn_mfma_f32_16x16x32_f16(A0.v, B.v, acc0, 0, 0, 0);
        acc1 = __builtin_amdgcn_mfma_f32_16x16x32_f16(A1.v, B.v, acc1, 0, 0, 0);
    }

    // C/D: col j = n15, row m = q*4 + r. Fused attention dots (reduce over j).
    const float as = a_src2[n15], ad = a_dst2[n15];
#pragma unroll
    for (int m = 0; m < 2; ++m) {
        const f32x4 acc = m ? acc1 : acc0;
#pragma unroll
        for (int r = 0; r < 4; ++r) {
            const int node = n0 + m * 64 + q * 4 + r;
            float ps = acc[r] * as;
            float pd = acc[r] * ad;
#pragma unroll
            for (int o = 1; o < 16; o <<= 1) {
                ps += __shfl_xor(ps, o, 64);
                pd += __shfl_xor(pd, o, 64);
            }
            if (node < N_NODES) {
                xw2h[(size_t)node * 16 + n15] = __float2half(acc[r]);  // 32B runs/quad
                if (n15 == 0) { al2[node] = ps; ar2[node] = pd; }
            }
        }
    }
}

// ---------------------------------------------------------------------------
// Layer 2 pull-aggregation: one wave per node; 32 edges in flight — mean
// degree 17 completes in ONE memory round (xw2h 3.2MB ~L2-resident).
// ---------------------------------------------------------------------------
__global__ __launch_bounds__(256)
void k_aggr2(const int* __restrict__ ssrc, const int* __restrict__ offs,
             const int* __restrict__ deg, const float* __restrict__ al2,
             const float* __restrict__ ar2, const __half* __restrict__ xw2h,
             const float* __restrict__ b2, float* __restrict__ out) {
    const int lane = threadIdx.x & 63;
    const int node = blockIdx.x * 4 + (threadIdx.x >> 6);
    const int j2 = lane & 7;                 // feature pair 2*j2, 2*j2+1
    const int eL = lane >> 3;                // 0..7
    const int beg = offs[node];
    const int n = deg[node];
    const float ard = ar2[node];
    float a0 = 0.f, a1 = 0.f, dnm = 0.f;
    for (int base = 0; base < n; base += 32) {
#pragma unroll
        for (int u = 0; u < 4; ++u) {
            const int e = base + u * 8 + eL;
            const bool p = e < n;
            const int s = ssrc[beg + (p ? e : 0)];
            float v = al2[s] + ard;
            v = v > 0.f ? v : NEG_SLOPE * v;
            const float w = p ? __expf(v) : 0.f;
            const float2 f = __half22float2(*(const __half2*)&xw2h[(size_t)s * 16 + j2 * 2]);
            a0 = fmaf(w, f.x, a0);
            a1 = fmaf(w, f.y, a1);
            dnm += w;
        }
    }
#pragma unroll
    for (int o = 8; o < 64; o <<= 1) {
        a0 += __shfl_xor(a0, o, 64);
        a1 += __shfl_xor(a1, o, 64);
        dnm += __shfl_xor(dnm, o, 64);
    }
    if (eL == 0) {
        out[(size_t)node * 16 + j2 * 2]     = a0 / dnm + b2[j2 * 2];
        out[(size_t)node * 16 + j2 * 2 + 1] = a1 / dnm + b2[j2 * 2 + 1];
    }
}

extern "C" void kernel_launch(void* const* d_in, const int* in_sizes, int n_in,
                              void* d_out, int out_size, void* d_ws, size_t ws_size,
                              hipStream_t stream) {
    const float* x      = (const float*)d_in[0];
    const int*   ei     = (const int*)d_in[1];
    const float* W1     = (const float*)d_in[2];
    const float* a_src1 = (const float*)d_in[3];
    const float* a_dst1 = (const float*)d_in[4];
    const float* b1     = (const float*)d_in[5];
    const float* W2     = (const float*)d_in[6];
    const float* a_src2 = (const float*)d_in[7];
    const float* a_dst2 = (const float*)d_in[8];
    const float* b2     = (const float*)d_in[9];
    float* out = (float*)d_out;

    // Workspace (byte-addressed). Aliases:
    //  - pairs (8.4MB packed) sits in out1h's region: consumed by k_fill3
    //    before k_aggr1 writes out1h.
    //  - xw2h/al2/ar2 sit in xw1h's region: written by k_gemm2m after k_aggr1
    //    is done with xw1h.
    //  - W1T/W2T/WaT1 live past the end (written once by k_prep; read-only).
    char* wsb = (char*)d_ws;
    __half* xw1h = (__half*)wsb;                                  // N*128 half (25.6 MB)
    __half* xw2h = (__half*)wsb;                                  // N*16 half (alias)
    float*  al2  = (float*)(wsb + (size_t)N_NODES * 16 * 2);      // N fp32 (alias)
    float*  ar2  = al2 + N_NODES;                                 // N fp32 (alias)
    __half* out1h = (__half*)(wsb + (size_t)N_NODES * 128 * 2);   // N*128 half (25.6 MB)
    int*    pairs = (int*)out1h;                                  // NBUCK*PBSTRIDE int (8.4 MB)
    float*  al1  = (float*)(wsb + (size_t)N_NODES * 128 * 4);     // N*4 fp32
    float*  ar1  = al1 + (size_t)N_NODES * 4;                     // N*4
    int* ibcnt = (int*)(ar1 + (size_t)N_NODES * 4);               // NBUCK (512 reserved)
    int* ioff  = ibcnt + 512;                                     // N
    int* ideg  = ioff + N_NODES;                                  // N
    int* isrc  = ideg + N_NODES;                                  // E_TOT
    _Float16* W1T  = (_Float16*)(isrc + E_TOT);                   // 128*128 f16 (32 KB)
    _Float16* W2T  = W1T + 128 * 128;                             // 16*128 f16 (4 KB)
    _Float16* WaT1 = W2T + 16 * 128;                              // 16*128 f16 (4 KB)

    // Parallel prep: transpose+cvt weights, fold attention vecs, zero bcnt.
    k_prep<<<10, 256, 0, stream>>>(W1, W2, a_src1, a_dst1, W1T, W2T, WaT1, ibcnt);

    // Merged: MFMA layer-1 GEMM (staged-x, M=64, W1T + balanced WaT1 tile)
    // + edge bucket partition.
    k_gemm1_part<<<NGEMM + NPART, 256, 0, stream>>>(x, W1T, WaT1, ei, ibcnt,
                                                    pairs, xw1h, al1, ar1);
    // Per-bucket counting sort -> CSR (ioff/ideg/isrc); 391 blocks (R7).
    k_fill3<<<NBUCK, 256, 0, stream>>>(pairs, ibcnt, ioff, ideg, isrc);

    // Layer 1 aggregation
    k_aggr1<<<N_NODES / 4, 256, 0, stream>>>(isrc, ioff, ideg, al1, ar1, xw1h, b1, out1h);

    // Layer 2 GEMM (MFMA, 2 M-tiles/wave, W2T B-frags) + fused attention dots
    k_gemm2m<<<(N_NODES + 127) / 128, 256, 0, stream>>>(out1h, W2T, a_src2, a_dst2, xw2h, al2, ar2);

    // Layer 2 aggregation
    k_aggr2<<<N_NODES / 4, 256, 0, stream>>>(isrc, ioff, ideg, al2, ar2, xw2h, b2, out);
}

// Round 11
// 294.459 us; speedup vs baseline: 1.0326x; 1.0326x over previous
//
#include <hip/hip_runtime.h>
#include <hip/hip_fp16.h>

#define N_NODES 100000
#define N_EDGES 1600000
#define E_TOT   (N_EDGES + N_NODES)   // 1,700,000 incl. self-loops
#define NEG_SLOPE 0.2f
#define PART_EPB 4096                 // edges per partition block
#define NBUCK 391                     // 256-node buckets (R7)
#define PBSTRIDE 5376                 // slots/bucket: mean 4352 + ~15 sigma
#define NGEMM ((N_NODES + 63) / 64)   // 1563 gemm blocks (64 rows each, R7)
#define NPART ((E_TOT + PART_EPB - 1) / PART_EPB)   // 416 partition blocks

using f16x8 = __attribute__((ext_vector_type(8))) _Float16;
using f32x4 = __attribute__((ext_vector_type(4))) float;
union H8 { f16x8 v; _Float16 h[8]; __half2 h2[4]; };
union H4 { __half2 h2[2]; uint2 u; };

// Journal (session): best = R7 @ 296.9us. Failed levers, do NOT retry:
//  R1  fuse gemm2 into aggr1 epilogue            +67us (serial tail on 2-iter gather loop)
//  R3  aggr1 MLP 8->16 in flight                 null  (random-gather HBM-efficiency bound)
//  R5  WaT fusion + SERIAL 1-block prep          +52us (bundle; serial prep on critical path)
//  R6  fill merged w/ gemm + standalone part     +14us (fill lost per-bucket parallelism)
//  R8  gemm1 M=128 (34.8KB LDS)                  +9us  (occupancy halved, shared w/ partition)
//  R9  W1T/W2T fp16 table B-frags                +0.7  (W-loads were hidden under MFMA)
//  R10 balanced WaT1 e-tile (epilogue-free)      +6.5  (epilogue shuffles were hidden too)
// Model: aggr1 = 244MB @ 2.7TB/s ~= HBM random-access efficiency ceiling
// (~43% of peak at 64-256B granularity); middle = 5 serial latency-bound
// stages with no single dominating fixable cost. This file = R7 exactly.

// ---------------------------------------------------------------------------
// Merged kernel: blocks < NGEMM do the layer-1 GEMM via MFMA (staged-x LDS
// tile, M=64). Blocks >= NGEMM do the edge bucket-partition (independent
// roles -> one dispatch, partition hides under the GEMM).
// ---------------------------------------------------------------------------
__global__ __launch_bounds__(256)
void k_gemm1_part(const float* __restrict__ x, const float* __restrict__ W1,
                  const float* __restrict__ a_src1, const float* __restrict__ a_dst1,
                  const int* __restrict__ ei, int* __restrict__ bcnt, int* __restrict__ pairs,
                  __half* __restrict__ xw1h, float* __restrict__ al1, float* __restrict__ ar1) {
    __shared__ int lcnt[NBUCK + 1];
    __shared__ int lbase[NBUCK + 1];
    __shared__ _Float16 sx[64][136];         // 17.4 KB; 272B row stride (2-way = free, m136)
    const int t = threadIdx.x;

    if (blockIdx.x >= NGEMM) {
        // ===== edge-partition role (391 buckets of 256 nodes) =====
        const int base = ((int)blockIdx.x - NGEMM) * PART_EPB;
        for (int i = t; i < NBUCK; i += 256) lcnt[i] = 0;
        __syncthreads();
        int sr[16], dr[16];
#pragma unroll
        for (int u = 0; u < 16; ++u) {
            const int e = base + u * 256 + t;    // coalesced
            if (e < E_TOT) {
                int s, d;
                if (e < N_EDGES) { s = ei[e]; d = ei[N_EDGES + e]; }
                else             { s = d = e - N_EDGES; }
                sr[u] = s; dr[u] = d;
                atomicAdd(&lcnt[d >> 8], 1);     // LDS
            } else dr[u] = -1;
        }
        __syncthreads();
        for (int i = t; i < NBUCK; i += 256) {
            const int c = lcnt[i];
            lbase[i] = (c > 0) ? atomicAdd(&bcnt[i], c) : 0;   // global, 1/bucket
            lcnt[i] = 0;
        }
        __syncthreads();
#pragma unroll
        for (int u = 0; u < 16; ++u) {
            if (dr[u] >= 0) {
                const int bk = dr[u] >> 8;
                const int r = atomicAdd(&lcnt[bk], 1);         // LDS
                pairs[(size_t)bk * PBSTRIDE + lbase[bk] + r] = (sr[u] << 8) | (dr[u] & 255);
            }
        }
        return;
    }

    // ===== MFMA GEMM role =====
    const int n0 = (int)blockIdx.x * 64;

    // Cooperative stage: 64 rows x 128 cols, f32 -> f16, coalesced float4.
    for (int i = t; i < 64 * 32; i += 256) {           // 8 iters/thread
        const int row = i >> 5;
        const int c4 = (i & 31) * 4;
        const int gr = n0 + row;
        const float4 xv = *(const float4*)&x[(size_t)(gr < N_NODES ? gr : N_NODES - 1) * 128 + c4];
        H4 tmp;
        tmp.h2[0] = __float22half2_rn(make_float2(xv.x, xv.y));
        tmp.h2[1] = __float22half2_rn(make_float2(xv.z, xv.w));
        *(uint2*)&sx[row][c4] = tmp.u;                 // 8B, 8B-aligned
    }
    __syncthreads();

    const int lane = t & 63;
    const int w = t >> 6;                    // wave id == head id
    const int q = lane >> 4;                 // quad
    const int n15 = lane & 15;
    const int j0 = (2 * w) * 16 + n15;       // col in tile 0 of this head
    const int j1 = (2 * w + 1) * 16 + n15;   // col in tile 1

    f32x4 acc[4][2] = {};                    // [m-group][n-tile]; static indices only

    for (int kt = 0; kt < 4; ++kt) {
        const int k0 = kt * 32 + q * 8;
        H8 A0, A1, A2, A3, B0, B1;
        A0.v = *(const f16x8*)&sx[n15][k0];            // 16B ds_read_b128
        A1.v = *(const f16x8*)&sx[16 + n15][k0];
        A2.v = *(const f16x8*)&sx[32 + n15][k0];
        A3.v = *(const f16x8*)&sx[48 + n15][k0];
        {
            float w0[8], w1[8];
#pragma unroll
            for (int i = 0; i < 8; ++i) {
                w0[i] = W1[(size_t)(k0 + i) * 128 + j0];   // 64B runs, L2-hot
                w1[i] = W1[(size_t)(k0 + i) * 128 + j1];
            }
#pragma unroll
            for (int i = 0; i < 4; ++i) {
                B0.h2[i] = __float22half2_rn(make_float2(w0[2 * i], w0[2 * i + 1]));
                B1.h2[i] = __float22half2_rn(make_float2(w1[2 * i], w1[2 * i + 1]));
            }
        }
        acc[0][0] = __builtin_amdgcn_mfma_f32_16x16x32_f16(A0.v, B0.v, acc[0][0], 0, 0, 0);
        acc[0][1] = __builtin_amdgcn_mfma_f32_16x16x32_f16(A0.v, B1.v, acc[0][1], 0, 0, 0);
        acc[1][0] = __builtin_amdgcn_mfma_f32_16x16x32_f16(A1.v, B0.v, acc[1][0], 0, 0, 0);
        acc[1][1] = __builtin_amdgcn_mfma_f32_16x16x32_f16(A1.v, B1.v, acc[1][1], 0, 0, 0);
        acc[2][0] = __builtin_amdgcn_mfma_f32_16x16x32_f16(A2.v, B0.v, acc[2][0], 0, 0, 0);
        acc[2][1] = __builtin_amdgcn_mfma_f32_16x16x32_f16(A2.v, B1.v, acc[2][1], 0, 0, 0);
        acc[3][0] = __builtin_amdgcn_mfma_f32_16x16x32_f16(A3.v, B0.v, acc[3][0], 0, 0, 0);
        acc[3][1] = __builtin_amdgcn_mfma_f32_16x16x32_f16(A3.v, B1.v, acc[3][1], 0, 0, 0);
    }

    // Epilogue: D col = n15-based j, row m*16 + q*4 + r. Fused attn dots.
    const float as0 = a_src1[j0], as1 = a_src1[j1];
    const float ad0 = a_dst1[j0], ad1 = a_dst1[j1];
#pragma unroll
    for (int m = 0; m < 4; ++m) {
#pragma unroll
        for (int r = 0; r < 4; ++r) {
            const int node = n0 + m * 16 + q * 4 + r;
            const float vA = acc[m][0][r], vB = acc[m][1][r];
            const bool ok = node < N_NODES;
            if (ok) {
                xw1h[(size_t)node * 128 + j0] = __float2half(vA);   // 32B runs/quad
                xw1h[(size_t)node * 128 + j1] = __float2half(vB);
            }
            float ps = vA * as0 + vB * as1;
            float pd = vA * ad0 + vB * ad1;
#pragma unroll
            for (int o = 1; o < 16; o <<= 1) {   // reduce over the 16 j-lanes (quad preserved)
                ps += __shfl_xor(ps, o, 64);
                pd += __shfl_xor(pd, o, 64);
            }
            if (n15 == 0 && ok) {
                al1[(size_t)node * 4 + w] = ps;
                ar1[(size_t)node * 4 + w] = pd;
            }
        }
    }
}

// ---------------------------------------------------------------------------
// k_fill3 (R7): one 256-thread block per 256-node bucket -> 391 blocks.
// LDS histogram + cursors counting sort; emits ioff/deg/ssrc.
// ---------------------------------------------------------------------------
__global__ __launch_bounds__(256)
void k_fill3(const int* __restrict__ pairs, const int* __restrict__ bcnt,
             int* __restrict__ ioff, int* __restrict__ deg, int* __restrict__ ssrc) {
    const int bucket = blockIdx.x;
    const int t = threadIdx.x;
    const int cnt = bcnt[bucket];
    __shared__ int lhist[256];
    __shared__ int lcur[256];
    __shared__ int wsum[4];
    __shared__ int sbc[NBUCK + 1];
    __shared__ int sbase;
    lhist[t] = 0;
    for (int i = t; i < NBUCK; i += 256) sbc[i] = bcnt[i];   // coalesced stage
    __syncthreads();
    if (t == 0) {                            // edges in all lower buckets (LDS, pipelined)
        int b = 0;
        for (int k = 0; k < bucket; ++k) b += sbc[k];
        sbase = b;
    }
    for (int i = t; i < cnt; i += 256) {
        const int p = pairs[(size_t)bucket * PBSTRIDE + i];
        atomicAdd(&lhist[p & 255], 1);
    }
    __syncthreads();
    const int v = lhist[t];
    int inc = v;
    const int lane = t & 63, wid = t >> 6;
#pragma unroll
    for (int o = 1; o < 64; o <<= 1) {
        const int nv = __shfl_up(inc, o, 64);
        if (lane >= o) inc += nv;
    }
    if (lane == 63) wsum[wid] = inc;
    __syncthreads();
    if (t == 0) {
        int acc = 0;
#pragma unroll
        for (int k = 0; k < 4; ++k) { const int tv = wsum[k]; wsum[k] = acc; acc += tv; }
    }
    __syncthreads();
    const int gofs = sbase + (inc - v) + wsum[wid];   // global CSR offset of node d
    const int d = bucket * 256 + t;
    if (d < N_NODES) { ioff[d] = gofs; deg[d] = v; }
    lcur[t] = gofs;
    __syncthreads();
    for (int i = t; i < cnt; i += 256) {
        const int p = pairs[(size_t)bucket * PBSTRIDE + i];
        const int pos = atomicAdd(&lcur[p & 255], 1);      // LDS
        ssrc[pos] = p >> 8;
    }
}

// ---------------------------------------------------------------------------
// Layer 1 pull-aggregation — FROZEN (VGPR 20, no epilogue preload; R1: no
// layer-2 fusion; R3: MLP-widening null -> random-gather HBM-efficiency
// bound). One wave per dst node, zero barriers; uint4 gathers, 8 in flight.
// ---------------------------------------------------------------------------
__global__ __launch_bounds__(256)
void k_aggr1(const int* __restrict__ ssrc, const int* __restrict__ offs,
             const int* __restrict__ deg, const float* __restrict__ al1,
             const float* __restrict__ ar1, const __half* __restrict__ xw1h,
             const float* __restrict__ b1, __half* __restrict__ out1h) {
    const int lane = threadIdx.x & 63;
    const int d = blockIdx.x * 4 + (threadIdx.x >> 6);
    const int g = lane >> 4;                 // edge group 0..3
    const int c = lane & 15;                 // col group: features 8c..8c+7
    const int h = c >> 2;                    // head of this col group
    const int beg = offs[d];
    const int n = deg[d];
    const float arh = ar1[(size_t)d * 4 + h];
    float acc[8] = {0.f, 0.f, 0.f, 0.f, 0.f, 0.f, 0.f, 0.f};
    float dnm = 0.f;

    for (int base = 0; base < n; base += 8) {
#pragma unroll
        for (int u = 0; u < 2; ++u) {
            const int e = base + u * 4 + g;
            const bool p = e < n;
            const int s = ssrc[beg + (p ? e : 0)];         // L1-hot (sequential)
            float v = al1[(size_t)s * 4 + h] + arh;        // broadcast gather
            v = v > 0.f ? v : NEG_SLOPE * v;
            const float w = p ? __expf(v) : 0.f;
            const uint4 rv = *(const uint4*)&xw1h[(size_t)s * 128 + c * 8];
            const float2 f0 = __half22float2(*(const __half2*)&rv.x);
            const float2 f1 = __half22float2(*(const __half2*)&rv.y);
            const float2 f2 = __half22float2(*(const __half2*)&rv.z);
            const float2 f3 = __half22float2(*(const __half2*)&rv.w);
            acc[0] = fmaf(w, f0.x, acc[0]); acc[1] = fmaf(w, f0.y, acc[1]);
            acc[2] = fmaf(w, f1.x, acc[2]); acc[3] = fmaf(w, f1.y, acc[3]);
            acc[4] = fmaf(w, f2.x, acc[4]); acc[5] = fmaf(w, f2.y, acc[5]);
            acc[6] = fmaf(w, f3.x, acc[6]); acc[7] = fmaf(w, f3.y, acc[7]);
            dnm += w;
        }
    }
#pragma unroll
    for (int i = 0; i < 8; ++i) {
        acc[i] += __shfl_xor(acc[i], 16, 64);
        acc[i] += __shfl_xor(acc[i], 32, 64);
    }
    dnm += __shfl_xor(dnm, 16, 64);
    dnm += __shfl_xor(dnm, 32, 64);
    if (g == 0) {
        const float rc = 1.f / dnm;
        const float4 b01 = *(const float4*)&b1[c * 8];
        const float4 b23 = *(const float4*)&b1[c * 8 + 4];
        const float bb[8] = {b01.x, b01.y, b01.z, b01.w, b23.x, b23.y, b23.z, b23.w};
        __half ho[8];
#pragma unroll
        for (int i = 0; i < 8; ++i) {
            const float hv = acc[i] * rc + bb[i];
            ho[i] = __float2half(hv > 0.f ? hv : 0.f);     // bias + ReLU
        }
        *(uint4*)&out1h[(size_t)d * 128 + c * 8] = *(uint4*)ho;
    }
}

// ---------------------------------------------------------------------------
// Layer 2 GEMM via MFMA. 128 nodes/block, 4 waves, 2 M-tiles/wave (R4/R7).
// A-frags direct 16B loads of out1h; W2 scalar-loads L1-hot; fused a2 dots.
// ---------------------------------------------------------------------------
__global__ __launch_bounds__(256)
void k_gemm2m(const __half* __restrict__ out1h, const float* __restrict__ W2,
              const float* __restrict__ a_src2, const float* __restrict__ a_dst2,
              __half* __restrict__ xw2h, float* __restrict__ al2, float* __restrict__ ar2) {
    const int t = threadIdx.x;
    const int lane = t & 63;
    const int w = t >> 6;
    const int q = lane >> 4;
    const int n15 = lane & 15;
    const int n0 = (int)blockIdx.x * 128 + w * 16;
    const int ra0 = n0 + n15;
    const int ra1 = n0 + 64 + n15;
    const size_t rowA0 = (ra0 < N_NODES) ? (size_t)ra0 : (size_t)(N_NODES - 1);
    const size_t rowA1 = (ra1 < N_NODES) ? (size_t)ra1 : (size_t)(N_NODES - 1);

    f32x4 acc0 = {0.f, 0.f, 0.f, 0.f}, acc1 = acc0;
#pragma unroll
    for (int kt = 0; kt < 4; ++kt) {
        const int k0 = kt * 32 + q * 8;
        H8 A0, A1, B;
        A0.v = *(const f16x8*)&out1h[rowA0 * 128 + k0];    // 16B, 32B runs/quad
        A1.v = *(const f16x8*)&out1h[rowA1 * 128 + k0];
        float wv[8];
#pragma unroll
        for (int i = 0; i < 8; ++i)
            wv[i] = W2[(size_t)(k0 + i) * 16 + n15];        // 64B runs, L1-hot
#pragma unroll
        for (int i = 0; i < 4; ++i)
            B.h2[i] = __float22half2_rn(make_float2(wv[2 * i], wv[2 * i + 1]));
        acc0 = __builtin_amdgcn_mfma_f32_16x16x32_f16(A0.v, B.v, acc0, 0, 0, 0);
        acc1 = __builtin_amdgcn_mfma_f32_16x16x32_f16(A1.v, B.v, acc1, 0, 0, 0);
    }

    // C/D: col j = n15, row m = q*4 + r. Fused attention dots (reduce over j).
    const float as = a_src2[n15], ad = a_dst2[n15];
#pragma unroll
    for (int m = 0; m < 2; ++m) {
        const f32x4 acc = m ? acc1 : acc0;
#pragma unroll
        for (int r = 0; r < 4; ++r) {
            const int node = n0 + m * 64 + q * 4 + r;
            float ps = acc[r] * as;
            float pd = acc[r] * ad;
#pragma unroll
            for (int o = 1; o < 16; o <<= 1) {
                ps += __shfl_xor(ps, o, 64);
                pd += __shfl_xor(pd, o, 64);
            }
            if (node < N_NODES) {
                xw2h[(size_t)node * 16 + n15] = __float2half(acc[r]);  // 32B runs/quad
                if (n15 == 0) { al2[node] = ps; ar2[node] = pd; }
            }
        }
    }
}

// ---------------------------------------------------------------------------
// Layer 2 pull-aggregation: one wave per node; 32 edges in flight — mean
// degree 17 completes in ONE memory round (xw2h 3.2MB ~L2-resident).
// ---------------------------------------------------------------------------
__global__ __launch_bounds__(256)
void k_aggr2(const int* __restrict__ ssrc, const int* __restrict__ offs,
             const int* __restrict__ deg, const float* __restrict__ al2,
             const float* __restrict__ ar2, const __half* __restrict__ xw2h,
             const float* __restrict__ b2, float* __restrict__ out) {
    const int lane = threadIdx.x & 63;
    const int node = blockIdx.x * 4 + (threadIdx.x >> 6);
    const int j2 = lane & 7;                 // feature pair 2*j2, 2*j2+1
    const int eL = lane >> 3;                // 0..7
    const int beg = offs[node];
    const int n = deg[node];
    const float ard = ar2[node];
    float a0 = 0.f, a1 = 0.f, dnm = 0.f;
    for (int base = 0; base < n; base += 32) {
#pragma unroll
        for (int u = 0; u < 4; ++u) {
            const int e = base + u * 8 + eL;
            const bool p = e < n;
            const int s = ssrc[beg + (p ? e : 0)];
            float v = al2[s] + ard;
            v = v > 0.f ? v : NEG_SLOPE * v;
            const float w = p ? __expf(v) : 0.f;
            const float2 f = __half22float2(*(const __half2*)&xw2h[(size_t)s * 16 + j2 * 2]);
            a0 = fmaf(w, f.x, a0);
            a1 = fmaf(w, f.y, a1);
            dnm += w;
        }
    }
#pragma unroll
    for (int o = 8; o < 64; o <<= 1) {
        a0 += __shfl_xor(a0, o, 64);
        a1 += __shfl_xor(a1, o, 64);
        dnm += __shfl_xor(dnm, o, 64);
    }
    if (eL == 0) {
        out[(size_t)node * 16 + j2 * 2]     = a0 / dnm + b2[j2 * 2];
        out[(size_t)node * 16 + j2 * 2 + 1] = a1 / dnm + b2[j2 * 2 + 1];
    }
}

extern "C" void kernel_launch(void* const* d_in, const int* in_sizes, int n_in,
                              void* d_out, int out_size, void* d_ws, size_t ws_size,
                              hipStream_t stream) {
    const float* x      = (const float*)d_in[0];
    const int*   ei     = (const int*)d_in[1];
    const float* W1     = (const float*)d_in[2];
    const float* a_src1 = (const float*)d_in[3];
    const float* a_dst1 = (const float*)d_in[4];
    const float* b1     = (const float*)d_in[5];
    const float* W2     = (const float*)d_in[6];
    const float* a_src2 = (const float*)d_in[7];
    const float* a_dst2 = (const float*)d_in[8];
    const float* b2     = (const float*)d_in[9];
    float* out = (float*)d_out;

    // Workspace (byte-addressed). Aliases:
    //  - pairs (8.4MB packed) sits in out1h's region: consumed by k_fill3
    //    before k_aggr1 writes out1h.
    //  - xw2h/al2/ar2 sit in xw1h's region: written by k_gemm2m after k_aggr1
    //    is done with xw1h.
    char* wsb = (char*)d_ws;
    __half* xw1h = (__half*)wsb;                                  // N*128 half (25.6 MB)
    __half* xw2h = (__half*)wsb;                                  // N*16 half (alias)
    float*  al2  = (float*)(wsb + (size_t)N_NODES * 16 * 2);      // N fp32 (alias)
    float*  ar2  = al2 + N_NODES;                                 // N fp32 (alias)
    __half* out1h = (__half*)(wsb + (size_t)N_NODES * 128 * 2);   // N*128 half (25.6 MB)
    int*    pairs = (int*)out1h;                                  // NBUCK*PBSTRIDE int (8.4 MB)
    float*  al1  = (float*)(wsb + (size_t)N_NODES * 128 * 4);     // N*4 fp32
    float*  ar1  = al1 + (size_t)N_NODES * 4;                     // N*4
    int* ibcnt = (int*)(ar1 + (size_t)N_NODES * 4);               // NBUCK (512 reserved)
    int* ioff  = ibcnt + 512;                                     // N
    int* ideg  = ioff + N_NODES;                                  // N
    int* isrc  = ideg + N_NODES;                                  // E_TOT

    hipMemsetAsync(ibcnt, 0, 512 * sizeof(int), stream);

    // Merged: MFMA layer-1 GEMM (staged-x, M=64) + edge bucket partition.
    k_gemm1_part<<<NGEMM + NPART, 256, 0, stream>>>(x, W1, a_src1, a_dst1,
                                                    ei, ibcnt, pairs, xw1h, al1, ar1);
    // Per-bucket counting sort -> CSR (ioff/ideg/isrc); 391 blocks (R7).
    k_fill3<<<NBUCK, 256, 0, stream>>>(pairs, ibcnt, ioff, ideg, isrc);

    // Layer 1 aggregation
    k_aggr1<<<N_NODES / 4, 256, 0, stream>>>(isrc, ioff, ideg, al1, ar1, xw1h, b1, out1h);

    // Layer 2 GEMM (MFMA, 2 M-tiles/wave) + fused attention dots
    k_gemm2m<<<(N_NODES + 127) / 128, 256, 0, stream>>>(out1h, W2, a_src2, a_dst2, xw2h, al2, ar2);

    // Layer 2 aggregation
    k_aggr2<<<N_NODES / 4, 256, 0, stream>>>(isrc, ioff, ideg, al2, ar2, xw2h, b2, out);
}